// Round 7
// baseline (762.272 us; speedup 1.0000x reference)
//
#include <hip/hip_runtime.h>
#include <hip/hip_bf16.h>

typedef __attribute__((ext_vector_type(8))) short short8;
typedef __attribute__((ext_vector_type(4))) float f32x4;
typedef __attribute__((ext_vector_type(4))) unsigned int u32x4;
typedef __attribute__((ext_vector_type(2))) unsigned int u32x2;

#define S_LEN 2048
#define D_DIM 128
#define BM 64         // q rows per block (4 waves x 16)
#define BN 64         // kv rows per tile
#define NQT 32        // S_LEN/BM

__device__ __forceinline__ unsigned short bfbits(float f) {
  return __builtin_bit_cast(unsigned short, __float2bfloat16(f));
}
__device__ __forceinline__ unsigned int pk2(float lo, float hi) {
  return (unsigned int)bfbits(lo) | ((unsigned int)bfbits(hi) << 16);
}
__device__ __forceinline__ float exp2f_hw(float x) {   // exp2; -inf -> 0
  float r;
  asm("v_exp_f32 %0, %1" : "=v"(r) : "v"(x));
  return r;
}

extern "C" __global__ void __launch_bounds__(256, 4)
fa_fwd_kernel(const float* __restrict__ Qg, const float* __restrict__ Kg,
              const float* __restrict__ Vg, float* __restrict__ Og)
{
  // 32 KB LDS total -> up to 5 blocks/CU (grid gives 4/CU average).
  __shared__ __align__(16) char smem[32768];
  char* Ksh = smem;            // K tile: 64 rows x 256B, XOR-swizzled
  char* Vsh = smem + 16384;    // Vt tile: 128 rows(d) x 128B(kv), XOR-swizzled

  const int bh = blockIdx.x;                  // XCD = bh%8 -> K/V L2 locality
  const int qt = (NQT - 1) - (int)blockIdx.y; // heavy q-tiles dispatch first
  const int m0 = qt * BM;
  const int tid = threadIdx.x;
  const int wv  = tid >> 6;
  const int ln  = tid & 63;
  const int l15 = ln & 15;
  const int lhi = ln >> 4;          // 0..3 (k-slice of MFMA fragment)
  const int vg4 = (tid & 31) * 4;   // V staging: first d of this thread
  const int vpb = tid >> 5;         // V staging: kv-quad base 0..7

  const size_t base = (size_t)bh * S_LEN * D_DIM;
  const float* Qb = Qg + base;
  const float* Kb = Kg + base;
  const float* Vb = Vg + base;
  float*       Ob = Og + base;

  const float scale = 0.12753102f;  // (1/sqrt(128)) * log2(e): log2-domain softmax
  const int wrow_lo = m0 + wv * 16;
  const int qg = wrow_lo + l15;     // this lane's own q row (swapped-QK layout)

  // QK A-row permutation sigma0(m)=8*(m>>2)+(m&3): S values land in PV B-frag order
  const int arow = ((l15 >> 2) << 3) + (l15 & 3);
  int krowb[4], kfx[4];
  #pragma unroll
  for (int c = 0; c < 4; ++c) {
    int kr = arow + (c & 1) * 4 + (c >> 1) * 32;
    krowb[c] = kr * 256;
    kfx[c] = ((kr & 3) | (((kr >> 3) & 1) << 2)) << 4;   // K swizzle for this row
  }

  // ---- Q B-frags (bf16, pre-scaled): lane -> q=l15-col, k=d=lhi*8+j ----
  short8 qf[4];
  {
    const float* qsrc = Qb + (size_t)qg * D_DIM + lhi * 8;
    #pragma unroll
    for (int kk = 0; kk < 4; ++kk) {
      f32x4 a = *(const f32x4*)(qsrc + kk * 32);
      f32x4 b = *(const f32x4*)(qsrc + kk * 32 + 4);
      u32x4 u;
      u[0] = pk2(a[0] * scale, a[1] * scale);
      u[1] = pk2(a[2] * scale, a[3] * scale);
      u[2] = pk2(b[0] * scale, b[1] * scale);
      u[3] = pk2(b[2] * scale, b[3] * scale);
      qf[kk] = __builtin_bit_cast(short8, u);
    }
  }

  // ---- staging helpers (256 threads, single-buffered K and V) ----
  auto load_k = [&](int t, f32x4* kr) {
    const float* Kt = Kb + (size_t)t * BN * D_DIM;
    #pragma unroll
    for (int i = 0; i < 8; ++i) {
      int idx = i * 256 + tid;
      kr[i] = *(const f32x4*)(Kt + (size_t)(idx >> 5) * D_DIM + (idx & 31) * 4);
    }
  };
  auto store_k = [&](const f32x4* kr) {
    #pragma unroll
    for (int i = 0; i < 8; ++i) {
      int idx = i * 256 + tid;
      int r = idx >> 5, c = idx & 31;
      int fk = ((r & 3) | (((r >> 3) & 1) << 2)) << 4;
      u32x2 w2; w2[0] = pk2(kr[i][0], kr[i][1]); w2[1] = pk2(kr[i][2], kr[i][3]);
      *(u32x2*)(Ksh + r * 256 + ((c * 8) ^ fk)) = w2;
    }
  };
  auto load_v = [&](int t, f32x4* vr) {
    const float* Vt = Vb + (size_t)t * BN * D_DIM;
    #pragma unroll
    for (int h = 0; h < 2; ++h) {
      const int vp = vpb + h * 8;
      #pragma unroll
      for (int r = 0; r < 4; ++r)
        vr[h * 4 + r] = *(const f32x4*)(Vt + (size_t)(4 * vp + r) * D_DIM + vg4);
    }
  };
  auto store_v = [&](const f32x4* vr) {
    #pragma unroll
    for (int h = 0; h < 2; ++h) {
      const int q = vpb + h * 8;    // kv quad
      #pragma unroll
      for (int j = 0; j < 4; ++j) {
        int jr = (j + tid) & 3;     // rotate write order: spread d&7 across lanes
        int d = vg4 + jr;
        u32x2 w2;
        w2[0] = pk2(vr[h * 4 + 0][jr], vr[h * 4 + 1][jr]);
        w2[1] = pk2(vr[h * 4 + 2][jr], vr[h * 4 + 3][jr]);
        *(u32x2*)(Vsh + ((d * 128 + q * 8) ^ ((d & 7) << 4))) = w2;
      }
    }
  };

  const f32x4 fzero = {0.f, 0.f, 0.f, 0.f};
  f32x4 oacc[8];                    // O^T: lane accumulates its own q column
  #pragma unroll
  for (int i = 0; i < 8; ++i) oacc[i] = fzero;
  float m_run = 8.0f;               // log2-domain; data row-max ~5 << 8+11.5
  float l_run = 0.f;

  const int ntiles = qt + 1;

  // ---- prologue: stage tile 0 ----
  {
    f32x4 st[8];
    load_k(0, st); store_k(st);
    load_v(0, st); store_v(st);
  }
  __syncthreads();

  for (int t = 0; t < ntiles; ++t) {
    const bool pf = (t + 1 < ntiles);
    f32x4 kr[8], vr[8];
    if (pf) { load_k(t + 1, kr); load_v(t + 1, vr); }  // issue early; land by store

    // ---- S^T = K Q^T (log2 domain) ----
    f32x4 sacc[4];
    __builtin_amdgcn_s_setprio(1);
    #pragma unroll
    for (int c = 0; c < 4; ++c) {
      sacc[c] = fzero;
      #pragma unroll
      for (int kk = 0; kk < 4; ++kk) {
        short8 kf = *(const short8*)(Ksh + krowb[c] + ((kk * 64 + lhi * 16) ^ kfx[c]));
        sacc[c] = __builtin_amdgcn_mfma_f32_16x16x32_bf16(kf, qf[kk], sacc[c], 0, 0, 0);
      }
    }
    __builtin_amdgcn_s_setprio(0);

    // ---- causal mask (diagonal tile only): kv = t*64 + 32(c>>1)+4(c&1)+8*lhi+r ----
    if (t == ntiles - 1) {
      #pragma unroll
      for (int c = 0; c < 4; ++c) {
        const int kvb = t * BN + (c >> 1) * 32 + (c & 1) * 4 + lhi * 8;
        #pragma unroll
        for (int r = 0; r < 4; ++r)
          if (kvb + r > qg) sacc[c][r] = -INFINITY;
      }
    }

    // ---- online softmax: speculative exp, max-check off critical path ----
    float mA[4];
    #pragma unroll
    for (int r = 0; r < 4; ++r)
      mA[r] = fmaxf(fmaxf(sacc[0][r], sacc[1][r]), fmaxf(sacc[2][r], sacc[3][r]));
    float mt = fmaxf(fmaxf(mA[0], mA[1]), fmaxf(mA[2], mA[3]));

    #pragma unroll
    for (int c = 0; c < 4; ++c)
      #pragma unroll
      for (int r = 0; r < 4; ++r)
        sacc[c][r] = exp2f_hw(sacc[c][r] - m_run);   // starts immediately

    mt = fmaxf(mt, __shfl_xor(mt, 16));
    mt = fmaxf(mt, __shfl_xor(mt, 32));
    if (!__all(mt <= m_run + 11.5f)) {               // rare rescale path
      const float m_new = fmaxf(m_run, mt);
      const float al = exp2f_hw(m_run - m_new);
      #pragma unroll
      for (int c = 0; c < 4; ++c)
        #pragma unroll
        for (int r = 0; r < 4; ++r) sacc[c][r] *= al;
      #pragma unroll
      for (int dc = 0; dc < 8; ++dc)
        #pragma unroll
        for (int r = 0; r < 4; ++r) oacc[dc][r] *= al;
      l_run *= al;
      m_run = m_new;
    }

    float sA[4];
    #pragma unroll
    for (int r = 0; r < 4; ++r)
      sA[r] = (sacc[0][r] + sacc[1][r]) + (sacc[2][r] + sacc[3][r]);
    float rs = (sA[0] + sA[1]) + (sA[2] + sA[3]);
    rs += __shfl_xor(rs, 16);
    rs += __shfl_xor(rs, 32);
    l_run += rs;

    // ---- P^T B-frags: pure in-lane packing (kv order matches by construction) ----
    short8 pfrag[2];
    #pragma unroll
    for (int w = 0; w < 2; ++w) {
      u32x4 u;
      u[0] = pk2(sacc[2 * w][0], sacc[2 * w][1]);
      u[1] = pk2(sacc[2 * w][2], sacc[2 * w][3]);
      u[2] = pk2(sacc[2 * w + 1][0], sacc[2 * w + 1][1]);
      u[3] = pk2(sacc[2 * w + 1][2], sacc[2 * w + 1][3]);
      pfrag[w] = __builtin_bit_cast(short8, u);
    }

    // ---- O^T += V^T P^T (conflict-free (d&7) swizzle) ----
    __builtin_amdgcn_s_setprio(1);
    #pragma unroll
    for (int dc = 0; dc < 8; ++dc) {
      const int drow = dc * 16 + l15;
      const int gx = (drow & 7) << 4;
      #pragma unroll
      for (int w = 0; w < 2; ++w) {
        short8 vf = *(const short8*)(Vsh + drow * 128 + ((w * 64 + lhi * 16) ^ gx));
        oacc[dc] = __builtin_amdgcn_mfma_f32_16x16x32_bf16(vf, pfrag[w], oacc[dc], 0, 0, 0);
      }
    }
    __builtin_amdgcn_s_setprio(0);

    __syncthreads();               // all waves done reading K/V LDS
    if (pf) { store_k(kr); store_v(vr); }
    __syncthreads();               // tile t+1 visible
  }

  // ---- epilogue: direct stores (4 lhi-lanes per l15 form one 64B line) ----
  const float invl = 1.0f / l_run;
  float* orow = Ob + (size_t)qg * D_DIM + lhi * 4;
  #pragma unroll
  for (int dc = 0; dc < 8; ++dc) {
    f32x4 o;
    #pragma unroll
    for (int r = 0; r < 4; ++r) o[r] = oacc[dc][r] * invl;
    *(f32x4*)(orow + dc * 16) = o;
  }
}

extern "C" void kernel_launch(void* const* d_in, const int* in_sizes, int n_in,
                              void* d_out, int out_size, void* d_ws, size_t ws_size,
                              hipStream_t stream) {
  const float* Q = (const float*)d_in[0];
  const float* K = (const float*)d_in[1];
  const float* V = (const float*)d_in[2];
  float* O = (float*)d_out;
  dim3 grid(32 /* B*H */, NQT);
  dim3 block(256);
  fa_fwd_kernel<<<grid, block, 0, stream>>>(Q, K, V, O);
}

// Round 8
// 417.064 us; speedup vs baseline: 1.8277x; 1.8277x over previous
//
#include <hip/hip_runtime.h>
#include <hip/hip_bf16.h>

typedef __attribute__((ext_vector_type(8))) short short8;
typedef __attribute__((ext_vector_type(4))) float f32x4;
typedef __attribute__((ext_vector_type(4))) unsigned int u32x4;
typedef __attribute__((ext_vector_type(2))) unsigned int u32x2;

#define S_LEN 2048
#define D_DIM 128
#define BM 128        // q rows per block = 4 waves x 32 (2 groups of 16)
#define BN 64         // kv rows per tile
#define NQT 16        // S_LEN/BM

__device__ __forceinline__ unsigned short bfbits(float f) {
  return __builtin_bit_cast(unsigned short, __float2bfloat16(f));
}
__device__ __forceinline__ unsigned int pk2(float lo, float hi) {
  return (unsigned int)bfbits(lo) | ((unsigned int)bfbits(hi) << 16);
}
__device__ __forceinline__ float exp2f_hw(float x) {   // exp2; -inf -> 0
  float r;
  asm("v_exp_f32 %0, %1" : "=v"(r) : "v"(x));
  return r;
}

extern "C" __global__ void __launch_bounds__(256, 2)
fa_fwd_kernel(const float* __restrict__ Qg, const float* __restrict__ Kg,
              const float* __restrict__ Vg, float* __restrict__ Og)
{
  // LDS 48KB: K single-buffered (64 x 256B, swizzled) + Vt double-buffered
  // (2 x 128 x 128B, swizzled). 2 blocks/CU (grid 512 = 2/CU).
  __shared__ __align__(16) char smem[49152];
  char* Ksh = smem;
  char* Vsh = smem + 16384;

  const int bh = blockIdx.x;                   // XCD = bh%8 -> K/V L2 locality
  const int qt = (NQT - 1) - (int)blockIdx.y;  // heavy q-tiles dispatch first
  const int m0 = qt * BM;
  const int tid = threadIdx.x;
  const int wv  = tid >> 6;
  const int ln  = tid & 63;
  const int l15 = ln & 15;
  const int lhi = ln >> 4;          // 0..3 (k-slice of MFMA fragment)
  const int vg4 = (tid & 31) * 4;   // V staging: first d of this thread
  const int vpb = tid >> 5;         // V staging: kv-quad base 0..7

  const size_t base = (size_t)bh * S_LEN * D_DIM;
  const float* Qb = Qg + base;
  const float* Kb = Kg + base;
  const float* Vb = Vg + base;
  float*       Ob = Og + base;

  const float scale = 0.12753102f;  // (1/sqrt(128)) * log2(e): log2-domain softmax
  const int wrow_lo = m0 + wv * 32; // wave owns 32 q rows (2 groups of 16)

  // QK A-row permutation sigma0(m)=8*(m>>2)+(m&3): S values land in PV B-frag order
  const int arow = ((l15 >> 2) << 3) + (l15 & 3);
  int krowb[4], kfx[4];
  #pragma unroll
  for (int c = 0; c < 4; ++c) {
    int kr = arow + (c & 1) * 4 + (c >> 1) * 32;
    krowb[c] = kr * 256;
    kfx[c] = ((kr & 3) | (((kr >> 3) & 1) << 2)) << 4;   // K swizzle for this row
  }

  // ---- Q B-frags, 2 groups (bf16, pre-scaled): lane -> q-col = l15 ----
  short8 qf[2][4];
  #pragma unroll
  for (int g = 0; g < 2; ++g) {
    const float* qsrc = Qb + (size_t)(wrow_lo + g * 16 + l15) * D_DIM + lhi * 8;
    #pragma unroll
    for (int kk = 0; kk < 4; ++kk) {
      f32x4 a = *(const f32x4*)(qsrc + kk * 32);
      f32x4 b = *(const f32x4*)(qsrc + kk * 32 + 4);
      u32x4 u;
      u[0] = pk2(a[0] * scale, a[1] * scale);
      u[1] = pk2(a[2] * scale, a[3] * scale);
      u[2] = pk2(b[0] * scale, b[1] * scale);
      u[3] = pk2(b[2] * scale, b[3] * scale);
      qf[g][kk] = __builtin_bit_cast(short8, u);
    }
  }

  // ---- staging helpers (256 threads; K and V windows NOT simultaneously live) ----
  auto load_k = [&](int t, f32x4* kr) {
    const float* Kt = Kb + (size_t)t * BN * D_DIM;
    #pragma unroll
    for (int i = 0; i < 8; ++i) {
      int idx = i * 256 + tid;
      kr[i] = *(const f32x4*)(Kt + (size_t)(idx >> 5) * D_DIM + (idx & 31) * 4);
    }
  };
  auto store_k = [&](const f32x4* kr) {
    #pragma unroll
    for (int i = 0; i < 8; ++i) {
      int idx = i * 256 + tid;
      int r = idx >> 5, c = idx & 31;
      int fk = ((r & 3) | (((r >> 3) & 1) << 2)) << 4;
      u32x2 w2; w2[0] = pk2(kr[i][0], kr[i][1]); w2[1] = pk2(kr[i][2], kr[i][3]);
      *(u32x2*)(Ksh + r * 256 + ((c * 8) ^ fk)) = w2;
    }
  };
  auto load_v = [&](int t, f32x4* vr) {
    const float* Vt = Vb + (size_t)t * BN * D_DIM;
    #pragma unroll
    for (int h = 0; h < 2; ++h) {
      const int vp = vpb + h * 8;
      #pragma unroll
      for (int r = 0; r < 4; ++r)
        vr[h * 4 + r] = *(const f32x4*)(Vt + (size_t)(4 * vp + r) * D_DIM + vg4);
    }
  };
  auto store_v = [&](char* vb, const f32x4* vr) {
    #pragma unroll
    for (int h = 0; h < 2; ++h) {
      const int q = vpb + h * 8;    // kv quad
      #pragma unroll
      for (int j = 0; j < 4; ++j) {
        int jr = (j + (tid >> 1)) & 3;   // spread (t&1, jr) over 8 slots -> 2-way max
        int d = vg4 + jr;
        u32x2 w2;
        w2[0] = pk2(vr[h * 4 + 0][jr], vr[h * 4 + 1][jr]);
        w2[1] = pk2(vr[h * 4 + 2][jr], vr[h * 4 + 3][jr]);
        *(u32x2*)(vb + ((d * 128 + q * 8) ^ ((d & 7) << 4))) = w2;
      }
    }
  };

  const f32x4 fzero = {0.f, 0.f, 0.f, 0.f};
  f32x4 oacc[2][8];                 // O^T per group: lane owns its q column
  #pragma unroll
  for (int g = 0; g < 2; ++g)
    #pragma unroll
    for (int i = 0; i < 8; ++i) oacc[g][i] = fzero;
  float m_run[2] = {8.0f, 8.0f};    // log2-domain; N(0,1) data row-max << 8+11.5
  float l_run[2] = {0.f, 0.f};

  const int ntiles = 2 * qt + 2;

  // ---- prologue: stage tile 0 (K -> Ksh, V -> Vsh buf0) ----
  {
    f32x4 st[8];
    load_k(0, st); store_k(st);
    load_v(0, st); store_v(Vsh, st);
  }
  __syncthreads();

  int cur = 0;
  for (int t = 0; t < ntiles; ++t) {
    const int kv0 = t * BN;
    const bool pf = (t + 1 < ntiles);
    const bool comp = (kv0 <= wrow_lo + 31);   // wave-uniform causal skip

    f32x4 kr[8];
    if (pf) load_k(t + 1, kr);                 // issue early; lands during QK

    f32x4 sacc[2][4];
    float mt[2];
    if (comp) {
      // ---- S^T = K Q^T (log2 domain): each kf read feeds BOTH q-groups ----
      __builtin_amdgcn_s_setprio(1);
      #pragma unroll
      for (int c = 0; c < 4; ++c) {
        sacc[0][c] = fzero; sacc[1][c] = fzero;
        #pragma unroll
        for (int kk = 0; kk < 4; ++kk) {
          short8 kf = *(const short8*)(Ksh + krowb[c] + ((kk * 64 + lhi * 16) ^ kfx[c]));
          sacc[0][c] = __builtin_amdgcn_mfma_f32_16x16x32_bf16(kf, qf[0][kk], sacc[0][c], 0, 0, 0);
          sacc[1][c] = __builtin_amdgcn_mfma_f32_16x16x32_bf16(kf, qf[1][kk], sacc[1][c], 0, 0, 0);
        }
      }
      __builtin_amdgcn_s_setprio(0);

      // ---- causal mask (diagonal region): kv = kv0 + 32(c>>1)+4(c&1)+8*lhi+r ----
      if (kv0 + BN - 1 > wrow_lo) {
        #pragma unroll
        for (int g = 0; g < 2; ++g) {
          const int qg = wrow_lo + g * 16 + l15;
          #pragma unroll
          for (int c = 0; c < 4; ++c) {
            const int kvb = kv0 + (c >> 1) * 32 + (c & 1) * 4 + lhi * 8;
            #pragma unroll
            for (int r = 0; r < 4; ++r)
              if (kvb + r > qg) sacc[g][c][r] = -INFINITY;
          }
        }
      }

      // ---- speculative exp2 (fixed m_run); max-tree runs alongside ----
      #pragma unroll
      for (int g = 0; g < 2; ++g) {
        float mA[4];
        #pragma unroll
        for (int r = 0; r < 4; ++r)
          mA[r] = fmaxf(fmaxf(sacc[g][0][r], sacc[g][1][r]),
                        fmaxf(sacc[g][2][r], sacc[g][3][r]));
        mt[g] = fmaxf(fmaxf(mA[0], mA[1]), fmaxf(mA[2], mA[3]));
        #pragma unroll
        for (int c = 0; c < 4; ++c)
          #pragma unroll
          for (int r = 0; r < 4; ++r)
            sacc[g][c][r] = exp2f_hw(sacc[g][c][r] - m_run[g]);
      }
    }

    __syncthreads();                 // all waves done reading Ksh
    if (pf) store_k(kr);             // K(t+1) -> Ksh (single buffer)

    f32x4 vr[8];
    if (pf) load_v(t + 1, vr);       // issue; lands during softmax+PV

    if (comp) {
      #pragma unroll
      for (int g = 0; g < 2; ++g) {
        // rare rescale path (spec-exp guard)
        float m = fmaxf(mt[g], __shfl_xor(mt[g], 16));
        m = fmaxf(m, __shfl_xor(m, 32));
        if (!__all(m <= m_run[g] + 11.5f)) {
          const float m_new = fmaxf(m_run[g], m);
          const float al = exp2f_hw(m_run[g] - m_new);
          #pragma unroll
          for (int c = 0; c < 4; ++c)
            #pragma unroll
            for (int r = 0; r < 4; ++r) sacc[g][c][r] *= al;
          #pragma unroll
          for (int dc = 0; dc < 8; ++dc)
            #pragma unroll
            for (int r = 0; r < 4; ++r) oacc[g][dc][r] *= al;
          l_run[g] *= al;
          m_run[g] = m_new;
        }
        float sA[4];
        #pragma unroll
        for (int r = 0; r < 4; ++r)
          sA[r] = (sacc[g][0][r] + sacc[g][1][r]) + (sacc[g][2][r] + sacc[g][3][r]);
        float rs = (sA[0] + sA[1]) + (sA[2] + sA[3]);
        rs += __shfl_xor(rs, 16);
        rs += __shfl_xor(rs, 32);
        l_run[g] += rs;
      }

      // ---- P^T B-frags (pure in-lane packing), per group ----
      short8 pfrag[2][2];
      #pragma unroll
      for (int g = 0; g < 2; ++g)
        #pragma unroll
        for (int w = 0; w < 2; ++w) {
          u32x4 u;
          u[0] = pk2(sacc[g][2 * w][0], sacc[g][2 * w][1]);
          u[1] = pk2(sacc[g][2 * w][2], sacc[g][2 * w][3]);
          u[2] = pk2(sacc[g][2 * w + 1][0], sacc[g][2 * w + 1][1]);
          u[3] = pk2(sacc[g][2 * w + 1][2], sacc[g][2 * w + 1][3]);
          pfrag[g][w] = __builtin_bit_cast(short8, u);
        }

      // ---- O^T += V^T P^T: each vf read feeds BOTH q-groups ----
      const char* Vl = Vsh + cur * 16384;
      __builtin_amdgcn_s_setprio(1);
      #pragma unroll
      for (int dc = 0; dc < 8; ++dc) {
        const int drow = dc * 16 + l15;
        const int gx = (drow & 7) << 4;
        #pragma unroll
        for (int w = 0; w < 2; ++w) {
          short8 vf = *(const short8*)(Vsh + cur * 16384 + drow * 128 + ((w * 64 + lhi * 16) ^ gx));
          oacc[0][dc] = __builtin_amdgcn_mfma_f32_16x16x32_bf16(vf, pfrag[0][w], oacc[0][dc], 0, 0, 0);
          oacc[1][dc] = __builtin_amdgcn_mfma_f32_16x16x32_bf16(vf, pfrag[1][w], oacc[1][dc], 0, 0, 0);
        }
      }
      __builtin_amdgcn_s_setprio(0);
      (void)Vl;
    }

    if (pf) store_v(Vsh + (cur ^ 1) * 16384, vr);  // V(t+1) -> alt buffer
    __syncthreads();                                // Ksh(t+1) + V alt visible
    cur ^= 1;
  }

  // ---- epilogue: direct stores (4 lhi-lanes per q-row form 64B chunks) ----
  #pragma unroll
  for (int g = 0; g < 2; ++g) {
    const float invl = 1.0f / l_run[g];
    float* orow = Ob + (size_t)(wrow_lo + g * 16 + l15) * D_DIM + lhi * 4;
    #pragma unroll
    for (int dc = 0; dc < 8; ++dc) {
      f32x4 o;
      #pragma unroll
      for (int r = 0; r < 4; ++r) o[r] = oacc[g][dc][r] * invl;
      *(f32x4*)(orow + dc * 16) = o;
    }
  }
}

extern "C" void kernel_launch(void* const* d_in, const int* in_sizes, int n_in,
                              void* d_out, int out_size, void* d_ws, size_t ws_size,
                              hipStream_t stream) {
  const float* Q = (const float*)d_in[0];
  const float* K = (const float*)d_in[1];
  const float* V = (const float*)d_in[2];
  float* O = (float*)d_out;
  dim3 grid(32 /* B*H */, NQT);
  dim3 block(256);
  fa_fwd_kernel<<<grid, block, 0, stream>>>(Q, K, V, O);
}

// Round 9
// 153.462 us; speedup vs baseline: 4.9672x; 2.7177x over previous
//
#include <hip/hip_runtime.h>
#include <hip/hip_bf16.h>

typedef __attribute__((ext_vector_type(8))) short short8;
typedef __attribute__((ext_vector_type(4))) float f32x4;
typedef __attribute__((ext_vector_type(4))) unsigned int u32x4;

#define S_LEN 2048
#define D_DIM 128
#define NT 32          // kv tiles of 64
#define NQT 16         // q blocks of BM=128
#define TILE_FRAG_BYTES 16384u            // 16 frags x 1KB per tile
#define VF_OFF ((size_t)32 * NT * TILE_FRAG_BYTES)   // 16 MB; total ws need 32 MB

__device__ __forceinline__ unsigned short bfbits(float f) {
  return __builtin_bit_cast(unsigned short, __float2bfloat16(f));
}
__device__ __forceinline__ unsigned int pk2(float lo, float hi) {
  return (unsigned int)bfbits(lo) | ((unsigned int)bfbits(hi) << 16);
}
__device__ __forceinline__ float exp2f_hw(float x) {   // exp2; -inf -> 0
  float r;
  asm("v_exp_f32 %0, %1" : "=v"(r) : "v"(x));
  return r;
}

// ---------------- prepass: K,V fp32 -> bf16 MFMA fragments in ws ----------------
// Kf[bh][t][f=c*4+kk][ln][8]: K[t*64 + sig0(l15)+4(c&1)+32(c>>1)][kk*32+lhi*8+j]
// Vf[bh][t][f=dc*2+w ][ln][8]: V[t*64 + w*32 + lhi*8 + j][dc*16 + l15]
extern "C" __global__ void __launch_bounds__(256)
fa_prepass_kernel(const float* __restrict__ Kg, const float* __restrict__ Vg,
                  char* __restrict__ ws)
{
  const unsigned gid = blockIdx.x * 256 + threadIdx.x;
  const unsigned g = gid & ((1u << 20) - 1);
  const int ln = g & 63, l15 = ln & 15, lhi = (ln >> 4) & 3;
  const int f  = (g >> 6) & 15;
  const int t  = (g >> 10) & 31;
  const int bh = g >> 15;
  char* dst = ws + ((size_t)(bh * NT + t) * 16 + f) * 1024 + ln * 16;
  if (gid < (1u << 20)) {
    const int c = f >> 2, kk = f & 3;
    const int row = t * 64 + ((l15 >> 2) << 3) + (l15 & 3) + ((c & 1) << 2) + ((c >> 1) << 5);
    const float* src = Kg + (size_t)bh * S_LEN * D_DIM + (size_t)row * D_DIM + kk * 32 + lhi * 8;
    f32x4 a = *(const f32x4*)src;
    f32x4 b = *(const f32x4*)(src + 4);
    u32x4 u;
    u[0] = pk2(a[0], a[1]); u[1] = pk2(a[2], a[3]);
    u[2] = pk2(b[0], b[1]); u[3] = pk2(b[2], b[3]);
    *(u32x4*)dst = u;
  } else {
    const int dc = f >> 1, w = f & 1;
    const float* src = Vg + (size_t)bh * S_LEN * D_DIM
                     + (size_t)(t * 64 + w * 32 + lhi * 8) * D_DIM + dc * 16 + l15;
    float v[8];
    #pragma unroll
    for (int j = 0; j < 8; ++j) v[j] = src[(size_t)j * D_DIM];
    u32x4 u;
    u[0] = pk2(v[0], v[1]); u[1] = pk2(v[2], v[3]);
    u[2] = pk2(v[4], v[5]); u[3] = pk2(v[6], v[7]);
    *(u32x4*)(dst + VF_OFF) = u;
  }
}

// ---------------- main: no LDS, no barriers, fragment-direct from L2 ----------------
extern "C" __global__ void __launch_bounds__(256, 2)
fa_fwd_kernel(const float* __restrict__ Qg, const char* __restrict__ ws,
              float* __restrict__ Og)
{
  const int bh = blockIdx.x;                   // XCD = bh%8: Kf+Vf = 4MB/XCD in L2
  const int qt = (NQT - 1) - (int)blockIdx.y;  // heavy q-tiles dispatch first
  const int m0 = qt * 128;
  const int tid = threadIdx.x;
  const int wv  = tid >> 6;
  const int ln  = tid & 63;
  const int l15 = ln & 15;
  const int lhi = ln >> 4;

  const float* Qb = Qg + (size_t)bh * S_LEN * D_DIM;
  float*       Ob = Og + (size_t)bh * S_LEN * D_DIM;
  const char*  kfb = ws + (size_t)bh * NT * TILE_FRAG_BYTES;
  const char*  vfb = kfb + VF_OFF;
  const int    voff = ln * 16;

  const float scale = 0.12753102f;  // (1/sqrt(128)) * log2(e): log2-domain softmax
  const int wrow_lo = m0 + wv * 32; // wave owns 32 q rows (2 groups of 16)

  // ---- Q B-frags, 2 groups (bf16, pre-scaled): lane -> its own q column ----
  short8 qf[2][4];
  #pragma unroll
  for (int g = 0; g < 2; ++g) {
    const float* qsrc = Qb + (size_t)(wrow_lo + g * 16 + l15) * D_DIM + lhi * 8;
    #pragma unroll
    for (int kk = 0; kk < 4; ++kk) {
      f32x4 a = *(const f32x4*)(qsrc + kk * 32);
      f32x4 b = *(const f32x4*)(qsrc + kk * 32 + 4);
      u32x4 u;
      u[0] = pk2(a[0] * scale, a[1] * scale);
      u[1] = pk2(a[2] * scale, a[3] * scale);
      u[2] = pk2(b[0] * scale, b[1] * scale);
      u[3] = pk2(b[2] * scale, b[3] * scale);
      qf[g][kk] = __builtin_bit_cast(short8, u);
    }
  }

  const f32x4 fzero = {0.f, 0.f, 0.f, 0.f};
  f32x4 oacc[2][8];                 // O^T per group (AGPR): lane owns its q column
  #pragma unroll
  for (int g = 0; g < 2; ++g)
    #pragma unroll
    for (int i = 0; i < 8; ++i) oacc[g][i] = fzero;
  float m_run[2] = {8.0f, 8.0f};    // log2-domain; N(0,1) row-max << 8+11.5
  float l_run[2] = {0.f, 0.f};

  const int ntw = wrow_lo / 64 + 1; // this wave's causal tile count

  for (int t = 0; t < ntw; ++t) {
    const char* kt = kfb + (size_t)t * TILE_FRAG_BYTES;
    const char* vt = vfb + (size_t)t * TILE_FRAG_BYTES;

    // ---- S^T = K Q^T (log2 domain); each kf feeds both q-groups ----
    f32x4 sacc[2][4];
    __builtin_amdgcn_s_setprio(1);
    #pragma unroll
    for (int c = 0; c < 4; ++c) {
      sacc[0][c] = fzero; sacc[1][c] = fzero;
      #pragma unroll
      for (int kk = 0; kk < 4; ++kk) {
        short8 kf = *(const short8*)(kt + (c * 4 + kk) * 1024 + voff);
        sacc[0][c] = __builtin_amdgcn_mfma_f32_16x16x32_bf16(kf, qf[0][kk], sacc[0][c], 0, 0, 0);
        sacc[1][c] = __builtin_amdgcn_mfma_f32_16x16x32_bf16(kf, qf[1][kk], sacc[1][c], 0, 0, 0);
      }
    }
    __builtin_amdgcn_s_setprio(0);

    // ---- causal mask (last tile): kv = t*64 + 32(c>>1)+4(c&1)+8*lhi+r ----
    if (t == ntw - 1) {
      #pragma unroll
      for (int g = 0; g < 2; ++g) {
        const int qg = wrow_lo + g * 16 + l15;
        #pragma unroll
        for (int c = 0; c < 4; ++c) {
          const int kvb = t * 64 + (c >> 1) * 32 + (c & 1) * 4 + lhi * 8;
          #pragma unroll
          for (int r = 0; r < 4; ++r)
            if (kvb + r > qg) sacc[g][c][r] = -INFINITY;
        }
      }
    }

    // ---- speculative exp2 (fixed m_run); rescale path ~never taken ----
    float mt[2];
    #pragma unroll
    for (int g = 0; g < 2; ++g) {
      float mA[4];
      #pragma unroll
      for (int r = 0; r < 4; ++r)
        mA[r] = fmaxf(fmaxf(sacc[g][0][r], sacc[g][1][r]),
                      fmaxf(sacc[g][2][r], sacc[g][3][r]));
      mt[g] = fmaxf(fmaxf(mA[0], mA[1]), fmaxf(mA[2], mA[3]));
      #pragma unroll
      for (int c = 0; c < 4; ++c)
        #pragma unroll
        for (int r = 0; r < 4; ++r)
          sacc[g][c][r] = exp2f_hw(sacc[g][c][r] - m_run[g]);
    }
    #pragma unroll
    for (int g = 0; g < 2; ++g) {
      float m = fmaxf(mt[g], __shfl_xor(mt[g], 16));
      m = fmaxf(m, __shfl_xor(m, 32));
      if (!__all(m <= m_run[g] + 11.5f)) {
        const float m_new = fmaxf(m_run[g], m);
        const float al = exp2f_hw(m_run[g] - m_new);
        #pragma unroll
        for (int c = 0; c < 4; ++c)
          #pragma unroll
          for (int r = 0; r < 4; ++r) sacc[g][c][r] *= al;
        #pragma unroll
        for (int dc = 0; dc < 8; ++dc)
          #pragma unroll
          for (int r = 0; r < 4; ++r) oacc[g][dc][r] *= al;
        l_run[g] *= al;
        m_run[g] = m_new;
      }
      float sA[4];
      #pragma unroll
      for (int r = 0; r < 4; ++r)
        sA[r] = (sacc[g][0][r] + sacc[g][1][r]) + (sacc[g][2][r] + sacc[g][3][r]);
      float rs = (sA[0] + sA[1]) + (sA[2] + sA[3]);
      rs += __shfl_xor(rs, 16);
      rs += __shfl_xor(rs, 32);
      l_run[g] += rs;
    }

    // ---- P^T B-frags: pure in-lane packing (kv order matches by construction) ----
    short8 pfrag[2][2];
    #pragma unroll
    for (int g = 0; g < 2; ++g)
      #pragma unroll
      for (int w = 0; w < 2; ++w) {
        u32x4 u;
        u[0] = pk2(sacc[g][2 * w][0], sacc[g][2 * w][1]);
        u[1] = pk2(sacc[g][2 * w][2], sacc[g][2 * w][3]);
        u[2] = pk2(sacc[g][2 * w + 1][0], sacc[g][2 * w + 1][1]);
        u[3] = pk2(sacc[g][2 * w + 1][2], sacc[g][2 * w + 1][3]);
        pfrag[g][w] = __builtin_bit_cast(short8, u);
      }

    // ---- O^T += V^T P^T; each vf feeds both q-groups ----
    __builtin_amdgcn_s_setprio(1);
    #pragma unroll
    for (int dc = 0; dc < 8; ++dc) {
      #pragma unroll
      for (int w = 0; w < 2; ++w) {
        short8 vf = *(const short8*)(vt + (dc * 2 + w) * 1024 + voff);
        oacc[0][dc] = __builtin_amdgcn_mfma_f32_16x16x32_bf16(vf, pfrag[0][w], oacc[0][dc], 0, 0, 0);
        oacc[1][dc] = __builtin_amdgcn_mfma_f32_16x16x32_bf16(vf, pfrag[1][w], oacc[1][dc], 0, 0, 0);
      }
    }
    __builtin_amdgcn_s_setprio(0);
  }

  // ---- epilogue: direct stores (d = dc*16 + lhi*4 + r on lane's own q row) ----
  #pragma unroll
  for (int g = 0; g < 2; ++g) {
    const float invl = 1.0f / l_run[g];
    float* orow = Ob + (size_t)(wrow_lo + g * 16 + l15) * D_DIM + lhi * 4;
    #pragma unroll
    for (int dc = 0; dc < 8; ++dc) {
      f32x4 o;
      #pragma unroll
      for (int r = 0; r < 4; ++r) o[r] = oacc[g][dc][r] * invl;
      *(f32x4*)(orow + dc * 16) = o;
    }
  }
}

extern "C" void kernel_launch(void* const* d_in, const int* in_sizes, int n_in,
                              void* d_out, int out_size, void* d_ws, size_t ws_size,
                              hipStream_t stream) {
  const float* Q = (const float*)d_in[0];
  const float* K = (const float*)d_in[1];
  const float* V = (const float*)d_in[2];
  float* O = (float*)d_out;
  char* ws = (char*)d_ws;
  // prepass: 2 * 2^20 threads
  fa_prepass_kernel<<<dim3(8192), dim3(256), 0, stream>>>(K, V, ws);
  dim3 grid(32 /* B*H */, NQT);
  fa_fwd_kernel<<<grid, dim3(256), 0, stream>>>(Q, ws, O);
}

// Round 10
// 88.743 us; speedup vs baseline: 8.5896x; 1.7293x over previous
//
#include <hip/hip_runtime.h>
#include <hip/hip_bf16.h>

typedef __attribute__((ext_vector_type(8))) short short8;
typedef __attribute__((ext_vector_type(4))) float f32x4;
typedef __attribute__((ext_vector_type(4))) unsigned int u32x4;

#define S_LEN 2048
#define D_DIM 128
#define NT 32          // kv tiles of 64
#define NQT 16         // q blocks of BM=128
#define TILE_FRAG_BYTES 16384u            // 16 frags x 1KB per tile (K or V)
#define VF_OFF ((size_t)32 * NT * TILE_FRAG_BYTES)   // 16 MB; ws need = 32 MB

__device__ __forceinline__ unsigned short bfbits(float f) {
  return __builtin_bit_cast(unsigned short, __float2bfloat16(f));
}
__device__ __forceinline__ unsigned int pk2(float lo, float hi) {
  return (unsigned int)bfbits(lo) | ((unsigned int)bfbits(hi) << 16);
}
__device__ __forceinline__ float exp2f_hw(float x) {   // exp2; -inf -> 0
  float r;
  asm("v_exp_f32 %0, %1" : "=v"(r) : "v"(x));
  return r;
}
__device__ __forceinline__ void gload16(const void* g, void* l) {
  // async global->LDS DMA: per-lane global src, wave-uniform LDS base (+lane*16)
  __builtin_amdgcn_global_load_lds(
      (const __attribute__((address_space(1))) unsigned int*)g,
      (__attribute__((address_space(3))) unsigned int*)l, 16, 0, 0);
}

// ---------------- prepass: K,V fp32 -> bf16 MFMA fragments in ws ----------------
// Kf[bh][t][f=c*4+kk][ln][8]: K[t*64 + sig0(l15)+4(c&1)+32(c>>1)][kk*32+lhi*8+j]
// Vf[bh][t][f=dc*2+w ][ln][8]: V[t*64 + w*32 + lhi*8 + j][dc*16 + l15]
extern "C" __global__ void __launch_bounds__(256)
fa_prepass_kernel(const float* __restrict__ Kg, const float* __restrict__ Vg,
                  char* __restrict__ ws)
{
  const unsigned gid = blockIdx.x * 256 + threadIdx.x;
  const unsigned g = gid & ((1u << 20) - 1);
  const int ln = g & 63, l15 = ln & 15, lhi = (ln >> 4) & 3;
  const int f  = (g >> 6) & 15;
  const int t  = (g >> 10) & 31;
  const int bh = g >> 15;
  char* dst = ws + ((size_t)(bh * NT + t) * 16 + f) * 1024 + ln * 16;
  if (gid < (1u << 20)) {
    const int c = f >> 2, kk = f & 3;
    const int row = t * 64 + ((l15 >> 2) << 3) + (l15 & 3) + ((c & 1) << 2) + ((c >> 1) << 5);
    const float* src = Kg + (size_t)bh * S_LEN * D_DIM + (size_t)row * D_DIM + kk * 32 + lhi * 8;
    f32x4 a = *(const f32x4*)src;
    f32x4 b = *(const f32x4*)(src + 4);
    u32x4 u;
    u[0] = pk2(a[0], a[1]); u[1] = pk2(a[2], a[3]);
    u[2] = pk2(b[0], b[1]); u[3] = pk2(b[2], b[3]);
    *(u32x4*)dst = u;
  } else {
    const int dc = f >> 1, w = f & 1;
    const float* src = Vg + (size_t)bh * S_LEN * D_DIM
                     + (size_t)(t * 64 + w * 32 + lhi * 8) * D_DIM + dc * 16 + l15;
    float v[8];
    #pragma unroll
    for (int j = 0; j < 8; ++j) v[j] = src[(size_t)j * D_DIM];
    u32x4 u;
    u[0] = pk2(v[0], v[1]); u[1] = pk2(v[2], v[3]);
    u[2] = pk2(v[4], v[5]); u[3] = pk2(v[6], v[7]);
    *(u32x4*)(dst + VF_OFF) = u;
  }
}

// -------- main: LDS double-buffer filled by global_load_lds DMA (no staging regs) --------
extern "C" __global__ void __launch_bounds__(256, 2)
fa_fwd_kernel(const float* __restrict__ Qg, const char* __restrict__ ws,
              float* __restrict__ Og)
{
  __shared__ __align__(16) char smem[2][32768];   // 64KB -> 2 blocks/CU

  const int bh = blockIdx.x;                   // XCD = bh%8: ws slice L2 locality
  const int qt = (NQT - 1) - (int)blockIdx.y;  // heavy q-tiles dispatch first
  const int m0 = qt * 128;
  const int tid = threadIdx.x;
  const int wv  = tid >> 6;
  const int ln  = tid & 63;
  const int l15 = ln & 15;
  const int lhi = ln >> 4;

  const float* Qb = Qg + (size_t)bh * S_LEN * D_DIM;
  float*       Ob = Og + (size_t)bh * S_LEN * D_DIM;
  const char*  kfb = ws + (size_t)bh * NT * TILE_FRAG_BYTES;
  const int    voff = ln * 16;

  const float scale = 0.12753102f;  // (1/sqrt(128)) * log2(e): log2-domain softmax
  const int wrow_lo = m0 + wv * 32; // wave owns 32 q rows (2 groups of 16)

  // ---- Q B-frags, 2 groups (bf16, pre-scaled): lane -> its own q column ----
  short8 qf[2][4];
  #pragma unroll
  for (int g = 0; g < 2; ++g) {
    const float* qsrc = Qb + (size_t)(wrow_lo + g * 16 + l15) * D_DIM + lhi * 8;
    #pragma unroll
    for (int kk = 0; kk < 4; ++kk) {
      f32x4 a = *(const f32x4*)(qsrc + kk * 32);
      f32x4 b = *(const f32x4*)(qsrc + kk * 32 + 4);
      u32x4 u;
      u[0] = pk2(a[0] * scale, a[1] * scale);
      u[1] = pk2(a[2] * scale, a[3] * scale);
      u[2] = pk2(b[0] * scale, b[1] * scale);
      u[3] = pk2(b[2] * scale, b[3] * scale);
      qf[g][kk] = __builtin_bit_cast(short8, u);
    }
  }

  // ---- staging: pure DMA, 8 fragments per wave (K frags 0-15, V frags 16-31) ----
  auto stage = [&](int t, char* buf) {
    const char* kt = kfb + (size_t)t * TILE_FRAG_BYTES;
    #pragma unroll
    for (int i = 0; i < 8; ++i) {
      const int fi = wv * 8 + i;                      // wave-uniform
      const size_t src_off = (fi < 16) ? (size_t)fi * 1024
                                       : VF_OFF + (size_t)(fi - 16) * 1024;
      gload16(kt + src_off + voff, buf + fi * 1024);
    }
  };

  const f32x4 fzero = {0.f, 0.f, 0.f, 0.f};
  f32x4 oacc[2][8];                 // O^T per group: lane owns its q column
  #pragma unroll
  for (int g = 0; g < 2; ++g)
    #pragma unroll
    for (int i = 0; i < 8; ++i) oacc[g][i] = fzero;
  float m_run[2] = {8.0f, 8.0f};    // log2-domain; N(0,1) row-max << 8+11.5
  float l_run[2] = {0.f, 0.f};

  const int ntiles = 2 * qt + 2;

  stage(0, smem[0]);
  __syncthreads();                  // drains vmcnt: tile 0 resident

  int cur = 0;
  for (int t = 0; t < ntiles; ++t) {
    const int kv0 = t * 64;
    const bool comp = (kv0 <= wrow_lo + 31);           // wave-uniform causal skip
    if (t + 1 < ntiles) stage(t + 1, smem[cur ^ 1]);   // async; lands by barrier

    if (comp) {
      const char* kt = smem[cur];
      const char* vt = smem[cur] + 16 * 1024;

      // ---- S^T = K Q^T (log2 domain); each kf feeds both q-groups ----
      f32x4 sacc[2][4];
      __builtin_amdgcn_s_setprio(1);
      #pragma unroll
      for (int c = 0; c < 4; ++c) {
        sacc[0][c] = fzero; sacc[1][c] = fzero;
        #pragma unroll
        for (int kk = 0; kk < 4; ++kk) {
          short8 kf = *(const short8*)(kt + (c * 4 + kk) * 1024 + voff);
          sacc[0][c] = __builtin_amdgcn_mfma_f32_16x16x32_bf16(kf, qf[0][kk], sacc[0][c], 0, 0, 0);
          sacc[1][c] = __builtin_amdgcn_mfma_f32_16x16x32_bf16(kf, qf[1][kk], sacc[1][c], 0, 0, 0);
        }
      }
      __builtin_amdgcn_s_setprio(0);

      // ---- causal mask (diagonal region): kv = kv0 + 32(c>>1)+4(c&1)+8*lhi+r ----
      if (kv0 + 63 > wrow_lo) {
        #pragma unroll
        for (int g = 0; g < 2; ++g) {
          const int qg = wrow_lo + g * 16 + l15;
          #pragma unroll
          for (int c = 0; c < 4; ++c) {
            const int kvb = kv0 + (c >> 1) * 32 + (c & 1) * 4 + lhi * 8;
            #pragma unroll
            for (int r = 0; r < 4; ++r)
              if (kvb + r > qg) sacc[g][c][r] = -INFINITY;
          }
        }
      }

      // ---- speculative exp2 (fixed m_run); rescale ~never taken ----
      float mt[2];
      #pragma unroll
      for (int g = 0; g < 2; ++g) {
        float mA[4];
        #pragma unroll
        for (int r = 0; r < 4; ++r)
          mA[r] = fmaxf(fmaxf(sacc[g][0][r], sacc[g][1][r]),
                        fmaxf(sacc[g][2][r], sacc[g][3][r]));
        mt[g] = fmaxf(fmaxf(mA[0], mA[1]), fmaxf(mA[2], mA[3]));
        #pragma unroll
        for (int c = 0; c < 4; ++c)
          #pragma unroll
          for (int r = 0; r < 4; ++r)
            sacc[g][c][r] = exp2f_hw(sacc[g][c][r] - m_run[g]);
      }
      #pragma unroll
      for (int g = 0; g < 2; ++g) {
        float m = fmaxf(mt[g], __shfl_xor(mt[g], 16));
        m = fmaxf(m, __shfl_xor(m, 32));
        if (!__all(m <= m_run[g] + 11.5f)) {
          const float m_new = fmaxf(m_run[g], m);
          const float al = exp2f_hw(m_run[g] - m_new);
          #pragma unroll
          for (int c = 0; c < 4; ++c)
            #pragma unroll
            for (int r = 0; r < 4; ++r) sacc[g][c][r] *= al;
          #pragma unroll
          for (int dc = 0; dc < 8; ++dc)
            #pragma unroll
            for (int r = 0; r < 4; ++r) oacc[g][dc][r] *= al;
          l_run[g] *= al;
          m_run[g] = m_new;
        }
        float sA[4];
        #pragma unroll
        for (int r = 0; r < 4; ++r)
          sA[r] = (sacc[g][0][r] + sacc[g][1][r]) + (sacc[g][2][r] + sacc[g][3][r]);
        float rs = (sA[0] + sA[1]) + (sA[2] + sA[3]);
        rs += __shfl_xor(rs, 16);
        rs += __shfl_xor(rs, 32);
        l_run[g] += rs;
      }

      // ---- P^T B-frags: pure in-lane packing ----
      short8 pfrag[2][2];
      #pragma unroll
      for (int g = 0; g < 2; ++g)
        #pragma unroll
        for (int w = 0; w < 2; ++w) {
          u32x4 u;
          u[0] = pk2(sacc[g][2 * w][0], sacc[g][2 * w][1]);
          u[1] = pk2(sacc[g][2 * w][2], sacc[g][2 * w][3]);
          u[2] = pk2(sacc[g][2 * w + 1][0], sacc[g][2 * w + 1][1]);
          u[3] = pk2(sacc[g][2 * w + 1][2], sacc[g][2 * w + 1][3]);
          pfrag[g][w] = __builtin_bit_cast(short8, u);
        }

      // ---- O^T += V^T P^T; each vf feeds both q-groups ----
      __builtin_amdgcn_s_setprio(1);
      #pragma unroll
      for (int dc = 0; dc < 8; ++dc) {
        #pragma unroll
        for (int w = 0; w < 2; ++w) {
          short8 vf = *(const short8*)(vt + (dc * 2 + w) * 1024 + voff);
          oacc[0][dc] = __builtin_amdgcn_mfma_f32_16x16x32_bf16(vf, pfrag[0][w], oacc[0][dc], 0, 0, 0);
          oacc[1][dc] = __builtin_amdgcn_mfma_f32_16x16x32_bf16(vf, pfrag[1][w], oacc[1][dc], 0, 0, 0);
        }
      }
      __builtin_amdgcn_s_setprio(0);
    }

    __syncthreads();   // drains stage(t+1) DMA + all waves done reading cur
    cur ^= 1;
  }

  // ---- epilogue: direct stores (d = dc*16 + lhi*4 + r on lane's own q row) ----
  #pragma unroll
  for (int g = 0; g < 2; ++g) {
    const float invl = 1.0f / l_run[g];
    float* orow = Ob + (size_t)(wrow_lo + g * 16 + l15) * D_DIM + lhi * 4;
    #pragma unroll
    for (int dc = 0; dc < 8; ++dc) {
      f32x4 o;
      #pragma unroll
      for (int r = 0; r < 4; ++r) o[r] = oacc[g][dc][r] * invl;
      *(f32x4*)(orow + dc * 16) = o;
    }
  }
}

extern "C" void kernel_launch(void* const* d_in, const int* in_sizes, int n_in,
                              void* d_out, int out_size, void* d_ws, size_t ws_size,
                              hipStream_t stream) {
  const float* Q = (const float*)d_in[0];
  const float* K = (const float*)d_in[1];
  const float* V = (const float*)d_in[2];
  float* O = (float*)d_out;
  char* ws = (char*)d_ws;
  fa_prepass_kernel<<<dim3(8192), dim3(256), 0, stream>>>(K, V, ws);
  dim3 grid(32 /* B*H */, NQT);
  fa_fwd_kernel<<<grid, dim3(256), 0, stream>>>(Q, ws, O);
}

// Round 11
// 86.885 us; speedup vs baseline: 8.7733x; 1.0214x over previous
//
#include <hip/hip_runtime.h>
#include <hip/hip_bf16.h>

typedef __attribute__((ext_vector_type(8))) short short8;
typedef __attribute__((ext_vector_type(4))) float f32x4;
typedef __attribute__((ext_vector_type(4))) unsigned int u32x4;

#define S_LEN 2048
#define D_DIM 128
#define NT 32          // kv tiles of 64
#define NQT 16         // q blocks of BM=128
#define TILE_FRAG_BYTES 16384u            // 16 frags x 1KB per tile (K or V)
#define VF_OFF ((size_t)32 * NT * TILE_FRAG_BYTES)   // 16 MB; ws need = 32 MB

__device__ __forceinline__ unsigned short bfbits(float f) {
  return __builtin_bit_cast(unsigned short, __float2bfloat16(f));
}
__device__ __forceinline__ unsigned int pk2(float lo, float hi) {
  return (unsigned int)bfbits(lo) | ((unsigned int)bfbits(hi) << 16);
}
__device__ __forceinline__ float exp2f_hw(float x) {   // exp2; -inf -> 0
  float r;
  asm("v_exp_f32 %0, %1" : "=v"(r) : "v"(x));
  return r;
}
__device__ __forceinline__ void gload16(const void* g, void* l) {
  // async global->LDS DMA: per-lane global src, wave-uniform LDS base (+lane*16)
  __builtin_amdgcn_global_load_lds(
      (const __attribute__((address_space(1))) unsigned int*)g,
      (__attribute__((address_space(3))) unsigned int*)l, 16, 0, 0);
}

// ---------------- prepass: K,V fp32 -> bf16 MFMA fragments in ws ----------------
// Kf[bh][t][f=c*4+kk][ln][8]: K[t*64 + sig0(l15)+4(c&1)+32(c>>1)][kk*32+lhi*8+j]
// Vf[bh][t][f=dc*2+w ][ln][8]: V[t*64 + w*32 + lhi*8 + j][dc*16 + l15]
extern "C" __global__ void __launch_bounds__(256)
fa_prepass_kernel(const float* __restrict__ Kg, const float* __restrict__ Vg,
                  char* __restrict__ ws)
{
  const unsigned gid = blockIdx.x * 256 + threadIdx.x;
  const unsigned g = gid & ((1u << 20) - 1);
  const int ln = g & 63, l15 = ln & 15, lhi = (ln >> 4) & 3;
  const int f  = (g >> 6) & 15;
  const int t  = (g >> 10) & 31;
  const int bh = g >> 15;
  char* dst = ws + ((size_t)(bh * NT + t) * 16 + f) * 1024 + ln * 16;
  if (gid < (1u << 20)) {
    const int c = f >> 2, kk = f & 3;
    const int row = t * 64 + ((l15 >> 2) << 3) + (l15 & 3) + ((c & 1) << 2) + ((c >> 1) << 5);
    const float* src = Kg + (size_t)bh * S_LEN * D_DIM + (size_t)row * D_DIM + kk * 32 + lhi * 8;
    f32x4 a = *(const f32x4*)src;
    f32x4 b = *(const f32x4*)(src + 4);
    u32x4 u;
    u[0] = pk2(a[0], a[1]); u[1] = pk2(a[2], a[3]);
    u[2] = pk2(b[0], b[1]); u[3] = pk2(b[2], b[3]);
    *(u32x4*)dst = u;
  } else {
    const int dc = f >> 1, w = f & 1;
    const float* src = Vg + (size_t)bh * S_LEN * D_DIM
                     + (size_t)(t * 64 + w * 32 + lhi * 8) * D_DIM + dc * 16 + l15;
    float v[8];
    #pragma unroll
    for (int j = 0; j < 8; ++j) v[j] = src[(size_t)j * D_DIM];
    u32x4 u;
    u[0] = pk2(v[0], v[1]); u[1] = pk2(v[2], v[3]);
    u[2] = pk2(v[4], v[5]); u[3] = pk2(v[6], v[7]);
    *(u32x4*)(dst + VF_OFF) = u;
  }
}

// ---- main: K via LDS DMA (double-buffered 32KB), V direct from ws (reg window) ----
extern "C" __global__ void __launch_bounds__(256, 2)
fa_fwd_kernel(const float* __restrict__ Qg, const char* __restrict__ ws,
              float* __restrict__ Og)
{
  __shared__ __align__(16) char smem[2][16384];   // K frags only

  const int bh = blockIdx.x;                   // XCD = bh%8: ws slice L2 locality
  const int by = (int)blockIdx.y;
  // balanced pairing: co-resident blocks (by, by+8) sum to 34 tiles
  const int qt = (by < 8) ? (15 - 2 * by) : (2 * (by - 8));
  const int m0 = qt * 128;
  const int tid = threadIdx.x;
  const int wv  = tid >> 6;
  const int ln  = tid & 63;
  const int l15 = ln & 15;
  const int lhi = ln >> 4;

  const float* Qb = Qg + (size_t)bh * S_LEN * D_DIM;
  float*       Ob = Og + (size_t)bh * S_LEN * D_DIM;
  const char*  kfb = ws + (size_t)bh * NT * TILE_FRAG_BYTES;
  const char*  vfbg = kfb + VF_OFF;            // V frags stay in global (L2)
  const int    voff = ln * 16;

  const float scale = 0.12753102f;  // (1/sqrt(128)) * log2(e): log2-domain softmax
  const int wrow_lo = m0 + wv * 32; // wave owns 32 q rows (2 groups of 16)

  // ---- Q B-frags, 2 groups (bf16, pre-scaled): lane -> its own q column ----
  short8 qf[2][4];
  #pragma unroll
  for (int g = 0; g < 2; ++g) {
    const float* qsrc = Qb + (size_t)(wrow_lo + g * 16 + l15) * D_DIM + lhi * 8;
    #pragma unroll
    for (int kk = 0; kk < 4; ++kk) {
      f32x4 a = *(const f32x4*)(qsrc + kk * 32);
      f32x4 b = *(const f32x4*)(qsrc + kk * 32 + 4);
      u32x4 u;
      u[0] = pk2(a[0] * scale, a[1] * scale);
      u[1] = pk2(a[2] * scale, a[3] * scale);
      u[2] = pk2(b[0] * scale, b[1] * scale);
      u[3] = pk2(b[2] * scale, b[3] * scale);
      qf[g][kk] = __builtin_bit_cast(short8, u);
    }
  }

  // ---- K staging: pure DMA, 4 fragments per wave ----
  auto stage_k = [&](int t, char* buf) {
    const char* kt = kfb + (size_t)t * TILE_FRAG_BYTES;
    #pragma unroll
    for (int i = 0; i < 4; ++i) {
      const int fi = wv * 4 + i;                 // wave-uniform frag id 0..15
      gload16(kt + (size_t)fi * 1024 + voff, buf + fi * 1024);
    }
  };

  const f32x4 fzero = {0.f, 0.f, 0.f, 0.f};
  f32x4 oacc[2][8];                 // O^T per group: lane owns its q column
  #pragma unroll
  for (int g = 0; g < 2; ++g)
    #pragma unroll
    for (int i = 0; i < 8; ++i) oacc[g][i] = fzero;
  float m_run[2] = {8.0f, 8.0f};    // log2-domain; N(0,1) row-max << 8+11.5
  float l_run[2] = {0.f, 0.f};

  const int ntiles = 2 * qt + 2;

  stage_k(0, smem[0]);
  __syncthreads();                  // drains vmcnt: K tile 0 resident

  int cur = 0;
  for (int t = 0; t < ntiles; ++t) {
    const int kv0 = t * 64;
    const bool comp = (kv0 <= wrow_lo + 31);             // wave-uniform causal skip
    if (t + 1 < ntiles) stage_k(t + 1, smem[cur ^ 1]);   // async; lands by barrier

    if (comp) {
      const char* kt = smem[cur];
      const char* vg = vfbg + (size_t)t * TILE_FRAG_BYTES;

      // ---- S^T = K Q^T (log2 domain); each kf feeds both q-groups ----
      f32x4 sacc[2][4];
      __builtin_amdgcn_s_setprio(1);
      #pragma unroll
      for (int c = 0; c < 4; ++c) {
        sacc[0][c] = fzero; sacc[1][c] = fzero;
        #pragma unroll
        for (int kk = 0; kk < 4; ++kk) {
          short8 kf = *(const short8*)(kt + (c * 4 + kk) * 1024 + voff);
          sacc[0][c] = __builtin_amdgcn_mfma_f32_16x16x32_bf16(kf, qf[0][kk], sacc[0][c], 0, 0, 0);
          sacc[1][c] = __builtin_amdgcn_mfma_f32_16x16x32_bf16(kf, qf[1][kk], sacc[1][c], 0, 0, 0);
        }
      }
      __builtin_amdgcn_s_setprio(0);

      // ---- V half A (dc 0-3) issued now: latency hides under mask+softmax ----
      short8 vfA[8];
      #pragma unroll
      for (int i = 0; i < 8; ++i)
        vfA[i] = *(const short8*)(vg + i * 1024 + voff);

      // ---- causal mask (diagonal region): kv = kv0 + 32(c>>1)+4(c&1)+8*lhi+r ----
      if (kv0 + 63 > wrow_lo) {
        #pragma unroll
        for (int g = 0; g < 2; ++g) {
          const int qg = wrow_lo + g * 16 + l15;
          #pragma unroll
          for (int c = 0; c < 4; ++c) {
            const int kvb = kv0 + (c >> 1) * 32 + (c & 1) * 4 + lhi * 8;
            #pragma unroll
            for (int r = 0; r < 4; ++r)
              if (kvb + r > qg) sacc[g][c][r] = -INFINITY;
          }
        }
      }

      // ---- speculative exp2 (fixed m_run); rescale ~never taken ----
      float mt[2];
      #pragma unroll
      for (int g = 0; g < 2; ++g) {
        float mA[4];
        #pragma unroll
        for (int r = 0; r < 4; ++r)
          mA[r] = fmaxf(fmaxf(sacc[g][0][r], sacc[g][1][r]),
                        fmaxf(sacc[g][2][r], sacc[g][3][r]));
        mt[g] = fmaxf(fmaxf(mA[0], mA[1]), fmaxf(mA[2], mA[3]));
        #pragma unroll
        for (int c = 0; c < 4; ++c)
          #pragma unroll
          for (int r = 0; r < 4; ++r)
            sacc[g][c][r] = exp2f_hw(sacc[g][c][r] - m_run[g]);
      }
      #pragma unroll
      for (int g = 0; g < 2; ++g) {
        float m = fmaxf(mt[g], __shfl_xor(mt[g], 16));
        m = fmaxf(m, __shfl_xor(m, 32));
        if (!__all(m <= m_run[g] + 11.5f)) {
          const float m_new = fmaxf(m_run[g], m);
          const float al = exp2f_hw(m_run[g] - m_new);
          #pragma unroll
          for (int c = 0; c < 4; ++c)
            #pragma unroll
            for (int r = 0; r < 4; ++r) sacc[g][c][r] *= al;
          #pragma unroll
          for (int dc = 0; dc < 8; ++dc)
            #pragma unroll
            for (int r = 0; r < 4; ++r) oacc[g][dc][r] *= al;
          l_run[g] *= al;
          m_run[g] = m_new;
        }
        float sA[4];
        #pragma unroll
        for (int r = 0; r < 4; ++r)
          sA[r] = (sacc[g][0][r] + sacc[g][1][r]) + (sacc[g][2][r] + sacc[g][3][r]);
        float rs = (sA[0] + sA[1]) + (sA[2] + sA[3]);
        rs += __shfl_xor(rs, 16);
        rs += __shfl_xor(rs, 32);
        l_run[g] += rs;
      }

      // ---- P^T B-frags: pure in-lane packing ----
      short8 pfrag[2][2];
      #pragma unroll
      for (int g = 0; g < 2; ++g)
        #pragma unroll
        for (int w = 0; w < 2; ++w) {
          u32x4 u;
          u[0] = pk2(sacc[g][2 * w][0], sacc[g][2 * w][1]);
          u[1] = pk2(sacc[g][2 * w][2], sacc[g][2 * w][3]);
          u[2] = pk2(sacc[g][2 * w + 1][0], sacc[g][2 * w + 1][1]);
          u[3] = pk2(sacc[g][2 * w + 1][2], sacc[g][2 * w + 1][3]);
          pfrag[g][w] = __builtin_bit_cast(short8, u);
        }

      // ---- V half B (dc 4-7) issued now: covered by PV half A ----
      short8 vfB[8];
      #pragma unroll
      for (int i = 0; i < 8; ++i)
        vfB[i] = *(const short8*)(vg + (8 + i) * 1024 + voff);

      // ---- O^T += V^T P^T from the register window ----
      __builtin_amdgcn_s_setprio(1);
      #pragma unroll
      for (int dc = 0; dc < 4; ++dc)
        #pragma unroll
        for (int w = 0; w < 2; ++w) {
          oacc[0][dc] = __builtin_amdgcn_mfma_f32_16x16x32_bf16(vfA[dc * 2 + w], pfrag[0][w], oacc[0][dc], 0, 0, 0);
          oacc[1][dc] = __builtin_amdgcn_mfma_f32_16x16x32_bf16(vfA[dc * 2 + w], pfrag[1][w], oacc[1][dc], 0, 0, 0);
        }
      #pragma unroll
      for (int dc = 4; dc < 8; ++dc)
        #pragma unroll
        for (int w = 0; w < 2; ++w) {
          oacc[0][dc] = __builtin_amdgcn_mfma_f32_16x16x32_bf16(vfB[(dc - 4) * 2 + w], pfrag[0][w], oacc[0][dc], 0, 0, 0);
          oacc[1][dc] = __builtin_amdgcn_mfma_f32_16x16x32_bf16(vfB[(dc - 4) * 2 + w], pfrag[1][w], oacc[1][dc], 0, 0, 0);
        }
      __builtin_amdgcn_s_setprio(0);
    }

    __syncthreads();   // drains stage_k(t+1) DMA + all waves done reading cur
    cur ^= 1;
  }

  // ---- epilogue: direct stores (d = dc*16 + lhi*4 + r on lane's own q row) ----
  #pragma unroll
  for (int g = 0; g < 2; ++g) {
    const float invl = 1.0f / l_run[g];
    float* orow = Ob + (size_t)(wrow_lo + g * 16 + l15) * D_DIM + lhi * 4;
    #pragma unroll
    for (int dc = 0; dc < 8; ++dc) {
      f32x4 o;
      #pragma unroll
      for (int r = 0; r < 4; ++r) o[r] = oacc[g][dc][r] * invl;
      *(f32x4*)(orow + dc * 16) = o;
    }
  }
}

extern "C" void kernel_launch(void* const* d_in, const int* in_sizes, int n_in,
                              void* d_out, int out_size, void* d_ws, size_t ws_size,
                              hipStream_t stream) {
  const float* Q = (const float*)d_in[0];
  const float* K = (const float*)d_in[1];
  const float* V = (const float*)d_in[2];
  float* O = (float*)d_out;
  char* ws = (char*)d_ws;
  fa_prepass_kernel<<<dim3(8192), dim3(256), 0, stream>>>(K, V, ws);
  dim3 grid(32 /* B*H */, NQT);
  fa_fwd_kernel<<<grid, dim3(256), 0, stream>>>(Q, ws, O);
}